// Round 6
// baseline (517.308 us; speedup 1.0000x reference)
//
#include <hip/hip_runtime.h>

#define INFV 1e8f

constexpr int NC = 512;      // columns (0-based u)
constexpr int NR = 512;      // rows (0-based y)
constexpr int RC = 72;       // ring columns = 9 panels of 8; 72*512*4 = 147456 B LDS
constexpr int PW = 8;        // panel width (cols)
constexpr int NSTEPS = 575;  // s = 0..574; lane l computes col u = s - l

// One wave (64 lanes) per batch. Lane l owns 0-based rows 8l..8l+7.
// Log-domain softmin identical to the R5 kernel that passed (absmax 2.0).
// LDS ring: slot(u) = u % 72 holds column u; element (u,y) at
//   ring[(u%72)*512 + (y ^ (u&31))]   (XOR swizzle -> <=2-way banks for both
//   the skewed wavefront access and uniform-column panel access).
// In-place: lane reads D from its slot rows, overwrites them with R.
// Every 8 steps (s = 8m+6, m=8..71): flush panel pf=m-8 (just completed this
// very step by lane 63) to global, refill its slots with panel pr=m+1 from
// registers (loaded at the previous event), issue loads for panel m+2.
__global__ __launch_bounds__(64, 1) void sdtw_ring(const float* __restrict__ D,
                                                   float* __restrict__ O) {
    __shared__ float ring[RC * NR];  // 147456 bytes

    const int b = blockIdx.x;
    const int l = threadIdx.x;  // 0..63
    const float* __restrict__ Dg = D + (size_t)b * NR * NC;
    float* __restrict__ Og = O + (size_t)b * NR * NC;
    const int y0 = l * 8;

    // ---- panel helpers: f = y*2 + qq enumerates the 1024 float4s of a
    // 512x8 panel; instr k: lane l -> f = k*64 + l (adjacent lanes share a row,
    // 16 rows per instr -> coalesced global; LDS banks = (l>>1)^salt, 2-way).
    float4 st[16];  // staging for the next refill panel

    auto panel_load = [&](int p) {
#pragma unroll
        for (int k = 0; k < 16; ++k) {
            const int f = k * 64 + l;
            const int y = f >> 1, qq = f & 1;
            st[k] = *(const float4*)(Dg + (size_t)y * NC + p * PW + qq * 4);
        }
    };
    auto panel_write = [&](int p) {  // st -> ring
#pragma unroll
        for (int k = 0; k < 16; ++k) {
            const int f = k * 64 + l;
            const int y = f >> 1, qq = f & 1;
            const int ub = p * PW + qq * 4;
#pragma unroll
            for (int j = 0; j < 4; ++j) {
                const int u = ub + j;
                ring[(u % RC) * NR + (y ^ (u & 31))] = ((const float*)&st[k])[j];
            }
        }
    };
    auto panel_flush = [&](int p) {  // ring -> global
#pragma unroll
        for (int k = 0; k < 16; ++k) {
            const int f = k * 64 + l;
            const int y = f >> 1, qq = f & 1;
            const int ub = p * PW + qq * 4;
            float4 v;
#pragma unroll
            for (int j = 0; j < 4; ++j) {
                const int u = ub + j;
                ((float*)&v)[j] = ring[(u % RC) * NR + (y ^ (u & 31))];
            }
            *(float4*)(Og + (size_t)y * NC + ub) = v;
        }
    };

    // ---- prologue: prefill panels 0..8 (ring full), stage loads for panel 9
    for (int p = 0; p < 9; ++p) {
        panel_load(p);
        panel_write(p);
    }
    panel_load(9);

    // DP state (identical semantics to R5)
    float prevR[8];
#pragma unroll
    for (int r = 0; r < 8; ++r) prevR[r] = INFV;
    float bp_r = (l == 0) ? 0.0f : INFV;  // R[y0-1, u-1]; lane0 corner R00=0
    float r_out = INFV;                   // R[y0+7, u] snapshot for lane l+1

    // dcur = D col u(s=0) (clamped to 0; only lane 0 valid at s=0)
    float dcur[8], dnext[8];
#pragma unroll
    for (int r = 0; r < 8; ++r) dcur[r] = ring[0 * NR + ((y0 + r) ^ 0)];

    for (int s = 0; s < NSTEPS; ++s) {
        const int u = s - l;
        const bool valid = (u >= 0) && (u < NC);

        // boundary handoff from lane l-1 (wave-lockstep, no barrier)
        float up_r = __shfl_up(r_out, 1);
        if (l == 0) up_r = INFV;  // row -1 boundary
        const float dAb = bp_r;   // R[y0-1, u-1]
        const float vAb = up_r;   // R[y0-1, u]
        bp_r = up_r;

        // prefetch next step's D column from the ring (latency hidden)
        {
            const int uc = min(max(u + 1, 0), NC - 1);
            const int base = (uc % RC) * NR;
            const int salt = uc & 31;
#pragma unroll
            for (int r = 0; r < 8; ++r) dnext[r] = ring[base + ((y0 + r) ^ salt)];
        }

        if (valid) {
            const int base = (u % RC) * NR;
            const int salt = u & 31;
            float diag = dAb, vert = vAb;
#pragma unroll
            for (int r = 0; r < 8; ++r) {
                const float a = diag, bb = vert, c = prevR[r];
                const float m = fminf(fminf(a, bb), c);
                const float e = __expf(m - a) + __expf(m - bb) + __expf(m - c);
                const float val = dcur[r] + (m - __logf(e));
                diag = prevR[r];  // becomes next row's diagonal
                vert = val;       // becomes next row's vertical
                prevR[r] = val;
                ring[base + ((y0 + r) ^ salt)] = val;  // overwrite D with R
            }
            r_out = prevR[7];
        }

#pragma unroll
        for (int r = 0; r < 8; ++r) dcur[r] = dnext[r];

        // panel event every 8 steps: s = 8m+6, m = 8..71
        if ((s & 7) == 6 && s >= 70) {
            const int m = s >> 3;
            panel_flush(m - 8);  // completed exactly this step (lane 63, col 8pf+7)
            const int pr = m + 1;
            if (pr < 64) {
                panel_write(pr);                     // staged 8 steps ago
                if (pr + 1 < 64) panel_load(pr + 1); // stage for next event
            }
        }
    }
}

extern "C" void kernel_launch(void* const* d_in, const int* in_sizes, int n_in,
                              void* d_out, int out_size, void* d_ws, size_t ws_size,
                              hipStream_t stream) {
    const float* D = (const float*)d_in[0];
    float* out = (float*)d_out;
    const int B = in_sizes[0] / (NR * NC);
    sdtw_ring<<<B, 64, 0, stream>>>(D, out);
}

// Round 8
// 433.635 us; speedup vs baseline: 1.1930x; 1.1930x over previous
//
#include <hip/hip_runtime.h>

#define INFV 1e8f
#define LN2F 0.69314718055994530942f
#define L2EF 1.44269504088896340736f

constexpr int NC = 512;      // columns (0-based u; 1-based j = u+1)
constexpr int NR = 512;      // rows (0-based y; 1-based i = y+1)
constexpr int RC = 72;       // ring columns (9 panels of 8); 72*512*4 = 147456 B
constexpr int PW = 8;        // panel width
constexpr int NSTEPS = 575;  // lane l computes column u = s - l

// One wave per batch; lane l owns rows 8l..8l+7. R6's ring/panel I/O (passed)
// + hybrid-domain compute core:
//   in-lane:   P = e^{-R} * 2^E  (E private per lane, renormed every 8 steps)
//   cross-lane: log-domain R values only (scale-free, renorm-immune)
// Per cell on the dependent chain: 2 adds + 1 mul. The exp (boundary receive)
// and log (output) sit once per step at the lane interface; e^{-D} is
// prefetched a step early. All transcendentals via __expf/__logf (e-base),
// which are the proven symbols in this harness (R7's __exp2f didn't compile).
// Ring element (u,y) at ring[(u%72)*512 + (y ^ (u&31))].
__global__ __launch_bounds__(64, 1) void sdtw_hyb(const float* __restrict__ D,
                                                  float* __restrict__ O) {
    __shared__ float ring[RC * NR];

    const int b = blockIdx.x;
    const int l = threadIdx.x;  // 0..63
    const float* __restrict__ Dg = D + (size_t)b * NR * NC;
    float* __restrict__ Og = O + (size_t)b * NR * NC;
    const int y0 = l * 8;

    float4 st[16];  // staging for next D panel

    auto panel_load = [&](int p) {
#pragma unroll
        for (int k = 0; k < 16; ++k) {
            const int f = k * 64 + l;
            const int y = f >> 1, qq = f & 1;
            st[k] = *(const float4*)(Dg + (size_t)y * NC + p * PW + qq * 4);
        }
    };
    auto panel_write = [&](int p) {  // st -> ring
#pragma unroll
        for (int k = 0; k < 16; ++k) {
            const int f = k * 64 + l;
            const int y = f >> 1, qq = f & 1;
            const int ub = p * PW + qq * 4;
#pragma unroll
            for (int j = 0; j < 4; ++j) {
                const int u = ub + j;
                ring[(u % RC) * NR + (y ^ (u & 31))] = ((const float*)&st[k])[j];
            }
        }
    };
    auto panel_flush = [&](int p) {  // ring (R values) -> global
#pragma unroll
        for (int k = 0; k < 16; ++k) {
            const int f = k * 64 + l;
            const int y = f >> 1, qq = f & 1;
            const int ub = p * PW + qq * 4;
            float4 v;
#pragma unroll
            for (int j = 0; j < 4; ++j) {
                const int u = ub + j;
                ((float*)&v)[j] = ring[(u % RC) * NR + (y ^ (u & 31))];
            }
            *(float4*)(Og + (size_t)y * NC + ub) = v;
        }
    };

    // prologue: fill panels 0..8 (cols 0..71), stage panel 9 in registers
    for (int p = 0; p < 9; ++p) { panel_load(p); panel_write(p); }
    panel_load(9);

    float prevP[8];  // stored P[row, u-1] at scale E; col 0 boundary -> 0
#pragma unroll
    for (int r = 0; r < 8; ++r) prevP[r] = 0.0f;
    float E = 0.0f;                          // private scale: stored = true * 2^E
    float bp_r = (l == 0) ? 0.0f : INFV;     // log R[8l, u] lagged -> diag-above
    float r_out = INFV;                      // log R[8l+8, u] for downstream

    float edcur[8];  // e^{-D[row, u]} for the current column (true scale)
#pragma unroll
    for (int r = 0; r < 8; ++r)
        edcur[r] = __expf(-ring[y0 + r]);  // col 0: slot 0, salt 0

    int uc_cur = 0;   // last prefetched column (clamped)
    int slot_cur = 0; // its ring slot ( == uc_cur % 72 )

    for (int s = 0; s < NSTEPS; ++s) {
        const int u = s - l;
        const bool valid = (u >= 0) && (u < NC);

        float up_r = __shfl_up(r_out, 1);  // log R[8l, u] (vert-above)
        if (l == 0) up_r = INFV;           // row boundary

        // column u's slot (prefetched last step) for the o-writes
        const int base_wr = slot_cur << 9;
        const int salt_wr = uc_cur & 31;

        // advance prefetch to column clamp(u+1)
        const int uc = min(max(u + 1, 0), NC - 1);
        if (uc > uc_cur) {
            uc_cur = uc;
            slot_cur = (slot_cur + 1 == RC) ? 0 : slot_cur + 1;
        }
        const int base_nx = slot_cur << 9;
        const int salt_nx = uc_cur & 31;
        float dnext[8];
#pragma unroll
        for (int r = 0; r < 8; ++r) dnext[r] = ring[base_nx + ((y0 + r) ^ salt_nx)];

        const float vab_log = up_r;  // R[8l, u+1 1-based]  (vert-above)
        const float dab_log = bp_r;  // R[8l, u   1-based]  (diag-above)
        bp_r = up_r;

        if (valid) {
            // cold-start scale adoption: pin incoming boundary to ~2^10
            if (u == 0) E = (l == 0) ? 0.0f : floorf(up_r * L2EF) + 10.0f;
            // stored P = e^{E*ln2 - R}; INFV/inf -> __expf(-huge) = 0 exactly
            const float vab = __expf(fmaf(E, LN2F, -vab_log));
            const float dab = __expf(fmaf(E, LN2F, -dab_log));
            float diag = dab, vert = vab;
#pragma unroll
            for (int r = 0; r < 8; ++r) {
                const float ss = (diag + vert) + prevP[r];     // chain: 2 add
                const float cur = edcur[r] * ss;               // chain: 1 mul
                const float o = fmaf(E, LN2F, -__logf(cur));   // off-chain
                ring[base_wr + ((y0 + r) ^ salt_wr)] = o;      // R replaces D
                diag = prevP[r];
                vert = cur;
                prevP[r] = cur;
                if (r == 7) r_out = o;  // log-domain handoff (scale-free)
            }
        }

        // renorm every 8 steps (phase 7; panel events on phase 6):
        // pin stored prevP[0] to ~2^10. E and prevP updated together; the
        // log-domain r_out is scale-free so renorm timing cannot desync it.
        if ((s & 7) == 7) {
            const int ex = (int)((__float_as_uint(prevP[0]) >> 23) & 0xffu);
            if (ex != 0) {  // skip not-yet-started lanes
                const int sh = 137 - ex;
                const float f = __uint_as_float((unsigned)(sh + 127) << 23);
                E += (float)sh;
#pragma unroll
                for (int r = 0; r < 8; ++r) prevP[r] *= f;
            }
        }

        // next column's e^{-D} (off the dependent chain)
#pragma unroll
        for (int r = 0; r < 8; ++r) edcur[r] = __expf(-dnext[r]);

        // panel event: s = 8m+6, m = 8..71 (panel m-8 completed this step)
        if ((s & 7) == 6 && s >= 70) {
            const int m = s >> 3;
            panel_flush(m - 8);
            const int pr = m + 1;
            if (pr < 64) {
                panel_write(pr);
                if (pr + 1 < 64) panel_load(pr + 1);
            }
        }
    }
}

extern "C" void kernel_launch(void* const* d_in, const int* in_sizes, int n_in,
                              void* d_out, int out_size, void* d_ws, size_t ws_size,
                              hipStream_t stream) {
    const float* D = (const float*)d_in[0];
    float* out = (float*)d_out;
    const int B = in_sizes[0] / (NR * NC);
    sdtw_hyb<<<B, 64, 0, stream>>>(D, out);
}

// Round 9
// 392.235 us; speedup vs baseline: 1.3189x; 1.1055x over previous
//
#include <hip/hip_runtime.h>

#define INFV 1e8f
#define LN2F 0.69314718055994530942f
#define L2EF 1.44269504088896340736f

constexpr int NC = 512;    // DP columns
constexpr int RW = 128;    // rows per wave
constexpr int NW = 4;      // waves per block
constexpr int RC = 72;     // ring columns per wave (9 panels of 8)
constexpr int NSW = 575;   // per-wave local steps (512 cols + 63 lane skew)
constexpr int WOFF = 72;   // wave-to-wave step offset (63 skew + 9 margin)
constexpr int NSG = NSW + (NW - 1) * WOFF;  // 791 global steps

// 4 waves per batch; wave w owns rows [128w,128w+128), lane owns 2 rows.
// Each wave = R8's proven structure (in-place D->R LDS ring, 8-col panels,
// P-domain cells with private scale E, log-domain lane handoff).
// Cross-wave boundary row 128w-1 via LDS mailbox (log domain, scale-free).
// Determinism: producer (wave w-1, its local step u+63 = global s-9) and
// consumer (wave w, global s) are 9 steps apart; __syncthreads() every 8
// steps bounds wave skew < 8 => >=1 barrier strictly between write and read.
__global__ __launch_bounds__(256, 1) void sdtw4(const float* __restrict__ D,
                                                float* __restrict__ O) {
    __shared__ float lds[NW * RC * RW + 3 * 128];  // 148992 B

    const int tid = threadIdx.x;
    const int w = tid >> 6, l = tid & 63;
    const int b = blockIdx.x;

    const float* __restrict__ Dg = D + (size_t)b * NC * 512 + (size_t)w * RW * NC;
    float* __restrict__ Og = O + (size_t)b * NC * 512 + (size_t)w * RW * NC;
    float* __restrict__ rg = lds + w * RC * RW;   // this wave's ring
    float* __restrict__ mb = lds + NW * RC * RW;  // mailbox [3][128]

    // panel helpers: 128 rows x 8 cols = 256 float4; f = k*64+l, y=f>>1, q=f&1
    float4 st[4];
    auto panel_load = [&](int p) {
#pragma unroll
        for (int k = 0; k < 4; ++k) {
            const int f = k * 64 + l, y = f >> 1, q = f & 1;
            st[k] = *(const float4*)(Dg + (size_t)y * NC + p * 8 + q * 4);
        }
    };
    auto panel_write = [&](int p) {
#pragma unroll
        for (int k = 0; k < 4; ++k) {
            const int f = k * 64 + l, y = f >> 1, q = f & 1;
            const int ub = p * 8 + q * 4;
#pragma unroll
            for (int j = 0; j < 4; ++j) {
                const int u = ub + j;
                rg[(u % RC) * RW + (y ^ (u & 31))] = ((const float*)&st[k])[j];
            }
        }
    };
    auto panel_flush = [&](int p) {
#pragma unroll
        for (int k = 0; k < 4; ++k) {
            const int f = k * 64 + l, y = f >> 1, q = f & 1;
            const int ub = p * 8 + q * 4;
            float4 v;
#pragma unroll
            for (int j = 0; j < 4; ++j) {
                const int u = ub + j;
                ((float*)&v)[j] = rg[(u % RC) * RW + (y ^ (u & 31))];
            }
            *(float4*)(Og + (size_t)y * NC + ub) = v;
        }
    };

    for (int p = 0; p < 9; ++p) { panel_load(p); panel_write(p); }
    panel_load(9);

    const int y0 = 2 * l;  // wave-local rows y0, y0+1
    float prevP0 = 0.0f, prevP1 = 0.0f;       // P[row, u-1] at scale E
    float E = 0.0f;
    float bp_r = (w == 0 && l == 0) ? 0.0f : INFV;  // log R[above, u-1]
    float r_out = INFV;                              // log R[y0+1, u]
    float ed0 = __expf(-rg[y0]);       // e^{-D[row, col 0]} (slot 0, salt 0)
    float ed1 = __expf(-rg[y0 + 1]);
    int uc_cur = 0, slot_cur = 0;

    for (int s = 0; s < NSG; ++s) {
        const int t = s - w * WOFF;  // wave-local step (uniform across wave)
        if (t >= 0 && t < NSW) {
            const int u = t - l;
            const bool valid = (u >= 0) && (u < NC);

            float up_r = __shfl_up(r_out, 1);  // log R[y0-1, u] from lane l-1
            if (l == 0)
                up_r = (w == 0) ? INFV : mb[(w - 1) * 128 + (u & 127)];

            const int base_wr = slot_cur * RW, salt_wr = uc_cur & 31;
            const int uc = min(max(u + 1, 0), NC - 1);
            if (uc > uc_cur) {
                uc_cur = uc;
                slot_cur = (slot_cur + 1 == RC) ? 0 : slot_cur + 1;
            }
            const int base_nx = slot_cur * RW, salt_nx = uc_cur & 31;
            const float dn0 = rg[base_nx + (y0 ^ salt_nx)];
            const float dn1 = rg[base_nx + ((y0 + 1) ^ salt_nx)];

            const float vab_log = up_r;  // R[above, u]
            const float dab_log = bp_r;  // R[above, u-1]
            bp_r = up_r;

            if (valid) {
                if (u == 0) E = (w == 0 && l == 0) ? 0.0f : floorf(up_r * L2EF) + 10.0f;
                const float vab = __expf(fmaf(E, LN2F, -vab_log));
                const float dab = __expf(fmaf(E, LN2F, -dab_log));
                // row y0: diag=dab, vert=vab, left=prevP0
                const float s0 = (dab + vab) + prevP0;
                const float c0 = ed0 * s0;
                const float o0 = fmaf(E, LN2F, -__logf(c0));
                // row y0+1: diag=prevP0(old), vert=c0, left=prevP1
                const float s1 = (prevP0 + c0) + prevP1;
                const float c1 = ed1 * s1;
                const float o1 = fmaf(E, LN2F, -__logf(c1));
                rg[base_wr + (y0 ^ salt_wr)] = o0;  // R replaces D in ring
                rg[base_wr + ((y0 + 1) ^ salt_wr)] = o1;
                prevP0 = c0; prevP1 = c1; r_out = o1;
                if (l == 63 && w < 3) mb[w * 128 + (u & 127)] = o1;
            }

            // renorm every 8 local steps (R8-proven cadence); r_out is
            // log-domain => renorm timing cannot desync the handoff
            if ((t & 7) == 7) {
                const int ex = (int)((__float_as_uint(prevP0) >> 23) & 0xffu);
                if (ex != 0) {
                    const int sh = 137 - ex;
                    const float f = __uint_as_float((unsigned)(sh + 127) << 23);
                    E += (float)sh;
                    prevP0 *= f; prevP1 *= f;
                }
            }

            ed0 = __expf(-dn0);  // next column's e^{-D} (off-chain)
            ed1 = __expf(-dn1);

            if ((t & 7) == 6 && t >= 70) {  // panel event (R8-identical)
                const int m = t >> 3;
                panel_flush(m - 8);
                const int pr = m + 1;
                if (pr < 64) {
                    panel_write(pr);
                    if (pr + 1 < 64) panel_load(pr + 1);
                }
            }
        }
        if ((s & 7) == 7) __syncthreads();  // uniform: bounds wave skew < 8
    }
}

extern "C" void kernel_launch(void* const* d_in, const int* in_sizes, int n_in,
                              void* d_out, int out_size, void* d_ws, size_t ws_size,
                              hipStream_t stream) {
    const float* D = (const float*)d_in[0];
    float* out = (float*)d_out;
    const int B = in_sizes[0] / (512 * 512);
    sdtw4<<<B, 256, 0, stream>>>(D, out);
}

// Round 10
// 331.112 us; speedup vs baseline: 1.5623x; 1.1846x over previous
//
#include <hip/hip_runtime.h>

#define INFV 1e8f
#define LN2F 0.69314718055994530942f
#define L2EF 1.44269504088896340736f

constexpr int NC = 512;    // DP columns
constexpr int RW = 128;    // rows per wave
constexpr int NW = 4;      // waves per block
constexpr int RC = 72;     // ring columns per wave (9 panels of 8)
constexpr int NSW = 575;   // per-wave local steps (512 cols + 63 lane skew)
constexpr int WOFF = 72;   // wave-to-wave step offset
constexpr int NSG = NSW + (NW - 1) * WOFF;  // 791 global steps

// R9 structure (4 waves/batch, 2 rows/lane, in-place LDS ring, mailbox) with
// the cross-lane handoff moved from ds_bpermute to DPP wave_shr:1 (VALU, no
// lgkmcnt), ring payload = e^{-D} (exp applied at panel staging), b64 ring
// accesses (salt = u & 30 keeps row pairs adjacent), and dab cached from the
// previous step's vab (one chain-exp per step instead of two).
static __device__ __forceinline__ float wave_shr1(float v, float old) {
    // lanes 1..63 <- lane-1's v; lane 0 <- old (bound_ctrl=false keeps old)
    return __int_as_float(__builtin_amdgcn_update_dpp(
        __float_as_int(old), __float_as_int(v), 0x138, 0xF, 0xF, false));
}

__global__ __launch_bounds__(256, 1) void sdtw5(const float* __restrict__ D,
                                                float* __restrict__ O) {
    __shared__ float lds[NW * RC * RW + 3 * 128];  // 148992 B

    const int tid = threadIdx.x;
    const int w = tid >> 6, l = tid & 63;
    const int b = blockIdx.x;

    const float* __restrict__ Dg = D + (size_t)b * NC * 512 + (size_t)w * RW * NC;
    float* __restrict__ Og = O + (size_t)b * NC * 512 + (size_t)w * RW * NC;
    float* __restrict__ rg = lds + w * RC * RW;   // this wave's ring
    float* __restrict__ mb = lds + NW * RC * RW;  // mailbox [3][128]

    // panel helpers: 128 rows x 8 cols = 256 float4; f = k*64+l, y=f>>1, q=f&1
    float4 st[4];
    auto panel_load = [&](int p) {
#pragma unroll
        for (int k = 0; k < 4; ++k) {
            const int f = k * 64 + l, y = f >> 1, q = f & 1;
            st[k] = *(const float4*)(Dg + (size_t)y * NC + p * 8 + q * 4);
        }
    };
    auto panel_write = [&](int p) {  // stores e^{-D}
#pragma unroll
        for (int k = 0; k < 4; ++k) {
            const int f = k * 64 + l, y = f >> 1, q = f & 1;
            const int ub = p * 8 + q * 4;
#pragma unroll
            for (int j = 0; j < 4; ++j) {
                const int u = ub + j;
                rg[(u % RC) * RW + (y ^ (u & 30))] = __expf(-((const float*)&st[k])[j]);
            }
        }
    };
    auto panel_flush = [&](int p) {  // ring (R values) -> global
#pragma unroll
        for (int k = 0; k < 4; ++k) {
            const int f = k * 64 + l, y = f >> 1, q = f & 1;
            const int ub = p * 8 + q * 4;
            float4 v;
#pragma unroll
            for (int j = 0; j < 4; ++j) {
                const int u = ub + j;
                ((float*)&v)[j] = rg[(u % RC) * RW + (y ^ (u & 30))];
            }
            *(float4*)(Og + (size_t)y * NC + ub) = v;
        }
    };

    for (int p = 0; p < 9; ++p) { panel_load(p); panel_write(p); }
    panel_load(9);

    const int y0 = 2 * l;  // wave-local rows y0, y0+1
    float prevP0 = 0.0f, prevP1 = 0.0f;  // P[row, u-1] at scale E
    float h01 = 0.0f;                    // prevP0 + prevP1 (precomputed off-chain)
    float E = 0.0f;                      // private scale: stored = true * 2^E
    float bp_r = (w == 0 && l == 0) ? 0.0f : INFV;  // log R[above, u-1]
    float r_out = INFV;                  // log R[y0+1, u] for downstream lane
    float vab_prev = 0.0f;               // P(R[y0-1, u-1]) at scale E (u>=1)
    float2 pd = *(const float2*)&rg[y0]; // e^{-D[rows, col 0]} (slot 0, salt 0)
    int uc_cur = 0, slot_cur = 0;
    float mb_cur = INFV;                 // mailbox value for lane0's current col

    for (int s = 0; s < NSG; ++s) {
        const int t = s - w * WOFF;  // wave-local step (uniform across wave)
        if (t >= 0 && t < NSW) {
            const int u = t - l;
            const bool valid = (u >= 0) && (u < NC);

            // cross-lane handoff: pure VALU, no LDS on the chain
            const float bnd = (w == 0) ? INFV : mb_cur;  // lane0 boundary, col u
            const float up_r = wave_shr1(r_out, bnd);    // log R[y0-1, u]

            const int base_wr = slot_cur * RW, salt_wr = uc_cur & 30;
            const int uc = min(max(u + 1, 0), NC - 1);
            if (uc > uc_cur) {
                uc_cur = uc;
                slot_cur = (slot_cur + 1 == RC) ? 0 : slot_cur + 1;
            }
            // next column's e^{-D}, one b64 read (used next step; latency hidden)
            const float2 pdn = *(const float2*)&rg[slot_cur * RW + (y0 ^ (uc_cur & 30))];

            const float dab_log = bp_r;  // log R[y0-1, u-1]
            bp_r = up_r;

            if (valid) {
                float dab;
                if (u == 0) {  // cold start: adopt scale pinning boundary ~2^10
                    E = (w == 0 && l == 0) ? 0.0f : floorf(up_r * L2EF) + 10.0f;
                    dab = __expf(fmaf(E, LN2F, -dab_log));
                } else {
                    dab = vab_prev;  // cached: exp(E*ln2 - up_r_prev)
                }
                const float vab = __expf(fmaf(E, LN2F, -up_r));  // chain exp
                const float s0 = (dab + vab) + prevP0;
                const float c0 = pd.x * s0;
                const float s1 = h01 + c0;       // h01 = prevP0 + prevP1
                const float c1 = pd.y * s1;
                const float o0 = fmaf(E, LN2F, -__logf(c0));  // off-chain
                const float o1 = fmaf(E, LN2F, -__logf(c1));  // on-chain (r_out)
                *(float2*)&rg[base_wr + (y0 ^ salt_wr)] = make_float2(o0, o1);
                prevP0 = c0; prevP1 = c1; h01 = c0 + c1;
                vab_prev = vab;
                r_out = o1;
                if (l == 63 && w < 3) mb[w * 128 + (u & 127)] = o1;
            }

            // renorm every 8 steps: pin stored prevP0 to ~2^10; rescale ALL
            // P-domain state (incl. vab_prev). Log-domain r_out is immune.
            if ((t & 7) == 7) {
                const int ex = (int)((__float_as_uint(prevP0) >> 23) & 0xffu);
                if (ex != 0) {
                    const int sh = 137 - ex;
                    const float f = __uint_as_float((unsigned)(sh + 127) << 23);
                    E += (float)sh;
                    prevP0 *= f; prevP1 *= f; h01 *= f; vab_prev *= f;
                }
            }
            pd = pdn;

            if ((t & 7) == 6 && t >= 70) {  // panel event (R9-identical timing)
                const int m = t >> 3;
                panel_flush(m - 8);
                const int pr = m + 1;
                if (pr < 64) {
                    panel_write(pr);
                    if (pr + 1 < 64) panel_load(pr + 1);
                }
            }
        }

        // mailbox prefetch for next local step (uniform broadcast read).
        // Producer wrote col tn at global s-8; one barrier strictly between.
        if (w > 0) {
            const int tn = t + 1;
            if (tn >= 0 && tn < NSW) mb_cur = mb[(w - 1) * 128 + (tn & 127)];
        }

        if ((s & 7) == 7) __syncthreads();  // bounds wave skew < 8
    }
}

extern "C" void kernel_launch(void* const* d_in, const int* in_sizes, int n_in,
                              void* d_out, int out_size, void* d_ws, size_t ws_size,
                              hipStream_t stream) {
    const float* D = (const float*)d_in[0];
    float* out = (float*)d_out;
    const int B = in_sizes[0] / (512 * 512);
    sdtw5<<<B, 256, 0, stream>>>(D, out);
}

// Round 12
// 266.003 us; speedup vs baseline: 1.9447x; 1.2448x over previous
//
#include <hip/hip_runtime.h>

#define INFV 1e8f
#define LN2F 0.69314718055994530942f
#define L2EF 1.44269504088896340736f

constexpr int NC = 512;   // DP columns
constexpr int RW = 128;   // rows per wave
constexpr int NW = 4;     // waves per block
constexpr int RC = 72;    // ring columns per wave (9 panels of 8)
constexpr int NSW = 575;  // local steps: t in [0,574]; lane l computes col u=t-l
constexpr int WOFF = 88;  // wave offset; multiple of 8; slack = WOFF-63 = 25 steps
constexpr int NGRP = (NSW + (NW - 1) * WOFF + 7) / 8;  // 105 groups of 8 steps

// R10 structure (4 waves/batch, 2 rows/lane, private in-place LDS ring, DPP
// handoff, P-domain cells + log-domain lane interface), no in-loop barriers.
// Cross-wave mailbox is FULL-WIDTH (512 cols/pair -> no wraparound, so the
// R11 producer flow-control spin -- whose uncapped `needp` deadlocked at
// needp>512 -- is deleted outright). One handshake remains: consumer waits
// for pflag[w-1] (cols committed, release/acquire, capped at 512), checked
// once per 8-step group, with a 2^24 spin guard so any protocol bug fails
// absmax instead of hanging the harness.
static __device__ __forceinline__ float wave_shr1(float v, float old) {
    // lanes 1..63 <- lane-1's v; lane 0 keeps `old` (bound_ctrl=false)
    return __int_as_float(__builtin_amdgcn_update_dpp(
        __float_as_int(old), __float_as_int(v), 0x138, 0xF, 0xF, false));
}

__global__ __launch_bounds__(256, 1) void sdtw7(const float* __restrict__ D,
                                                float* __restrict__ O) {
    __shared__ float ring[NW * RC * RW];  // 147456 B (private per wave)
    __shared__ float mbox[3 * NC];        // full-width boundary rows (6144 B)
    __shared__ int pflag[4];

    const int tid = threadIdx.x;
    const int w = tid >> 6, l = tid & 63;
    const int b = blockIdx.x;

    if (tid < 4) pflag[tid] = 0;
    __syncthreads();  // once, before the loop; no barriers inside

    const float* __restrict__ Dg = D + (size_t)b * NC * 512 + (size_t)w * RW * NC;
    float* __restrict__ Og = O + (size_t)b * NC * 512 + (size_t)w * RW * NC;
    float* __restrict__ rg = ring + w * RC * RW;

    // panel helpers: 128 rows x 8 cols = 256 float4; f = k*64+l, y=f>>1, q=f&1
    float4 st[4];
    auto panel_load = [&](int p) {
#pragma unroll
        for (int k = 0; k < 4; ++k) {
            const int f = k * 64 + l, y = f >> 1, q = f & 1;
            st[k] = *(const float4*)(Dg + (size_t)y * NC + p * 8 + q * 4);
        }
    };
    auto panel_write = [&](int p) {  // stores e^{-D}
#pragma unroll
        for (int k = 0; k < 4; ++k) {
            const int f = k * 64 + l, y = f >> 1, q = f & 1;
            const int ub = p * 8 + q * 4;
#pragma unroll
            for (int j = 0; j < 4; ++j) {
                const int u = ub + j;
                rg[(u % RC) * RW + (y ^ (u & 30))] = __expf(-((const float*)&st[k])[j]);
            }
        }
    };
    auto panel_flush = [&](int p) {  // ring (R values) -> global
#pragma unroll
        for (int k = 0; k < 4; ++k) {
            const int f = k * 64 + l, y = f >> 1, q = f & 1;
            const int ub = p * 8 + q * 4;
            float4 v;
#pragma unroll
            for (int j = 0; j < 4; ++j) {
                const int u = ub + j;
                ((float*)&v)[j] = rg[(u % RC) * RW + (y ^ (u & 30))];
            }
            *(float4*)(Og + (size_t)y * NC + ub) = v;
        }
    };

    for (int p = 0; p < 9; ++p) { panel_load(p); panel_write(p); }
    panel_load(9);

    const int y0 = 2 * l;
    float prevP0 = 0.0f, prevP1 = 0.0f;  // P[row, u-1] at scale E
    float h01 = 0.0f;                    // prevP0 + prevP1
    float E = 0.0f;                      // private scale
    float bp_r = (w == 0 && l == 0) ? 0.0f : INFV;  // log R[above, u-1]
    float r_out = INFV;                  // log R[y0+1, u]
    float vab_prev = 0.0f;               // cached P(R[above, u-1])
    float2 pd = *(const float2*)&rg[y0]; // e^{-D} col 0 (slot 0, salt 0)
    int uc_cur = 0, slot_cur = 0;
    float mb_cur = INFV;

    for (int g = 0; g < NGRP; ++g) {
        const int tb = 8 * g - WOFF * w;  // local t of phase 0 (multiple of 8)
        const int h = tb >> 3;            // local group index

        // consumer handshake: group h reads mbox cols [8h, 8h+8] (incl. the
        // phase-7 prefetch); h=-1 prefetches col 0 only. Guarded spin.
        if (w > 0 && h >= -1 && h <= 63) {
            const int need = min(8 * h + 9, NC);
            int guard = 0;
            while (__hip_atomic_load(&pflag[w - 1], __ATOMIC_ACQUIRE,
                                     __HIP_MEMORY_SCOPE_WORKGROUP) < need &&
                   ++guard < (1 << 24)) {}
        }

#pragma unroll
        for (int ph = 0; ph < 8; ++ph) {
            const int t = tb + ph;  // (t & 7) == ph since WOFF % 8 == 0
            if (t >= 0 && t < NSW) {
                const int u = t - l;
                const bool valid = (u >= 0) && (u < NC);

                const float bnd = (w == 0) ? INFV : mb_cur;
                const float up_r = wave_shr1(r_out, bnd);  // log R[y0-1, u]

                const int base_wr = slot_cur * RW, salt_wr = uc_cur & 30;
                const int uc = min(max(u + 1, 0), NC - 1);
                if (uc > uc_cur) {
                    uc_cur = uc;
                    slot_cur = (slot_cur + 1 == RC) ? 0 : slot_cur + 1;
                }
                const float2 pdn =
                    *(const float2*)&rg[slot_cur * RW + (y0 ^ (uc_cur & 30))];

                const float dab_log = bp_r;  // log R[y0-1, u-1]
                bp_r = up_r;

                if (valid) {
                    float dab;
                    if (u == 0) {  // cold start: adopt scale, pin boundary ~2^10
                        E = (w == 0 && l == 0) ? 0.0f : floorf(up_r * L2EF) + 10.0f;
                        dab = __expf(fmaf(E, LN2F, -dab_log));
                    } else {
                        dab = vab_prev;
                    }
                    const float vab = __expf(fmaf(E, LN2F, -up_r));  // chain exp
                    const float s0 = (dab + vab) + prevP0;
                    const float c0 = pd.x * s0;
                    const float s1 = h01 + c0;
                    const float c1 = pd.y * s1;
                    const float o0 = fmaf(E, LN2F, -__logf(c0));
                    const float o1 = fmaf(E, LN2F, -__logf(c1));
                    *(float2*)&rg[base_wr + (y0 ^ salt_wr)] = make_float2(o0, o1);
                    prevP0 = c0; prevP1 = c1; h01 = c0 + c1;
                    vab_prev = vab;
                    r_out = o1;
                    if (l == 63 && w < 3) mbox[w * NC + u] = o1;
                }

                if (ph == 7) {  // renorm: pin stored prevP0 ~2^10
                    const int ex = (int)((__float_as_uint(prevP0) >> 23) & 0xffu);
                    if (ex != 0) {
                        const int sh = 137 - ex;
                        const float f = __uint_as_float((unsigned)(sh + 127) << 23);
                        E += (float)sh;
                        prevP0 *= f; prevP1 *= f; h01 *= f; vab_prev *= f;
                    }
                }
                pd = pdn;

                if (ph == 6 && t >= 70) {  // panel event (private ring, no sync)
                    const int m = t >> 3;
                    panel_flush(m - 8);
                    const int pr = m + 1;
                    if (pr < 64) {
                        panel_write(pr);
                        if (pr + 1 < 64) panel_load(pr + 1);
                    }
                }
            }
            // mailbox prefetch for next step (covered by this group's handshake)
            if (w > 0) {
                const int tn = t + 1;
                if (tn >= 0 && tn < NC) mb_cur = mbox[(w - 1) * NC + tn];
            }
        }

        // producer publish (lane 0; release orders prior LDS writes).
        // cols committed by lane 63 after phase 7: 0..tb-56 -> count tb-55.
        if (l == 0 && w < 3) {
            const int cnt = tb - 55;
            if (cnt >= 1) {
                __hip_atomic_store(&pflag[w], min(cnt, NC), __ATOMIC_RELEASE,
                                   __HIP_MEMORY_SCOPE_WORKGROUP);
            }
        }
    }
}

extern "C" void kernel_launch(void* const* d_in, const int* in_sizes, int n_in,
                              void* d_out, int out_size, void* d_ws, size_t ws_size,
                              hipStream_t stream) {
    const float* D = (const float*)d_in[0];
    float* out = (float*)d_out;
    const int B = in_sizes[0] / (512 * 512);
    sdtw7<<<B, 256, 0, stream>>>(D, out);
}